// Round 21
// baseline (627.744 us; speedup 1.0000x reference)
//
#include <hip/hip_runtime.h>
#include <hip/hip_bf16.h>

// ---------------------------------------------------------------------------
// MoE transformer block on MI355X (gfx950).
// B=2,S=2048,D=1024,H=16,hd=64,F=4096,E=8,K=2, all inputs f32, output f32.
// R21 = R20/R18 base (615us) + split-KV flash: causal q-tiles 16..31 are
// split into two KV-half work units (each <=16 kv-tiles) -> 1536 uniform
// blocks instead of 1024 blocks with 1..32-tile spread; partial (o,m,l)
// written to the dead wo_part region; merge_k recombines (standard online-
// softmax two-way merge) and emits split-bf16 ao.
// ---------------------------------------------------------------------------

typedef float fx4 __attribute__((ext_vector_type(4)));
typedef short sx4 __attribute__((ext_vector_type(4)));
typedef short sx8 __attribute__((ext_vector_type(8)));
typedef int ix2 __attribute__((ext_vector_type(2)));
typedef int ix4 __attribute__((ext_vector_type(4)));

#define DEVFN static __device__ __forceinline__
#define MFMA16(a, b, c) __builtin_amdgcn_mfma_f32_16x16x32_bf16((a), (b), (c), 0, 0, 0)

typedef __attribute__((address_space(1))) const void GASV;
typedef __attribute__((address_space(3))) void LASV;

DEVFN short f2bf(float f) {
  unsigned u = __float_as_uint(f);
  return (short)((u + 0x7FFFu + ((u >> 16) & 1u)) >> 16);
}
DEVFN float bf2f(short s) { return __uint_as_float(((unsigned)(unsigned short)s) << 16); }

DEVFN int cvt_pk_bf16(float a, float b) {
  int r;
  asm("v_cvt_pk_bf16_f32 %0, %1, %2" : "=v"(r) : "v"(a), "v"(b));
  return r;
}

DEVFN void gll16(const short* g, short* l) {
  __builtin_amdgcn_global_load_lds((GASV*)g, (LASV*)l, 16, 0, 0);
}

// chunk swizzle: BK=64 -> row&7; BK=32 -> fold row bit2 into 2-bit chunk idx.
template <int BK>
DEVFN int swzr(int row) {
  if constexpr (BK == 64)
    return row & 7;
  else
    return (row ^ (row >> 2)) & 3;
}

DEVFN float fast_gelu(float x) {
  // tanh-approx gelu (matches jax.nn.gelu approximate=True)
  float u = 0.7978845608028654f * (x + 0.044715f * x * x * x);
  float e = __expf(2.0f * u);
  float t = 1.0f - 2.0f / (1.0f + e);
  return 0.5f * x * (1.0f + t);
}

DEVFN float wsum64(float v) {
#pragma unroll
  for (int m = 1; m < 64; m <<= 1) v += __shfl_xor(v, m);
  return v;
}

// ---------------------------------------------------------------------------
// transpose+convert: f32 [z][R][C] -> bf16 [z][C][R] (hi, and optional lo)
// ---------------------------------------------------------------------------
template <int SPLIT>
__global__ __launch_bounds__(256) void transpose_k(const float* in, short* oh, short* ol,
                                                   int R, int C) {
  __shared__ float t[64][65];
  const int c0 = blockIdx.x * 64, r0 = blockIdx.y * 64;
  const long long bofs = (long long)blockIdx.z * R * C;
  in += bofs;
  oh += bofs;
  if (SPLIT) ol += bofs;
  const int tid = threadIdx.x;
  const int rr = tid >> 4, cc4 = (tid & 15) * 4;
#pragma unroll
  for (int i = 0; i < 4; ++i) {
    int r = i * 16 + rr;
    fx4 v = *(const fx4*)(in + (long long)(r0 + r) * C + c0 + cc4);
    t[r][cc4] = v.x;
    t[r][cc4 + 1] = v.y;
    t[r][cc4 + 2] = v.z;
    t[r][cc4 + 3] = v.w;
  }
  __syncthreads();
#pragma unroll
  for (int i = 0; i < 4; ++i) {
    int oc = i * 16 + rr;  // output row = c0+oc
    sx4 hv, lv;
#pragma unroll
    for (int j = 0; j < 4; ++j) {
      float v = t[cc4 + j][oc];
      short hi = f2bf(v);
      hv[j] = hi;
      if (SPLIT) lv[j] = f2bf(v - bf2f(hi));
    }
    *(sx4*)(oh + (long long)(c0 + oc) * R + r0 + cc4) = hv;
    if (SPLIT) *(sx4*)(ol + (long long)(c0 + oc) * R + r0 + cc4) = lv;
  }
}

// ---------------------------------------------------------------------------
// RMSNorm: f32 [4096][1024] -> bf16 hi (+lo). one block per row.
// ---------------------------------------------------------------------------
template <int SPLIT>
__global__ __launch_bounds__(256) void rms_k(const float* x, const float* w, short* hh,
                                             short* hl) {
  const int row = blockIdx.x, tid = threadIdx.x;
  const fx4 v = ((const fx4*)(x + (long long)row * 1024))[tid];
  float ss = v.x * v.x + v.y * v.y + v.z * v.z + v.w * v.w;
  ss = wsum64(ss);
  __shared__ float red[4];
  if ((tid & 63) == 0) red[tid >> 6] = ss;
  __syncthreads();
  ss = red[0] + red[1] + red[2] + red[3];
  const float rr = rsqrtf(ss * (1.0f / 1024.0f) + 1e-6f);
  const fx4 wv = ((const fx4*)w)[tid];
  float vals[4] = {v.x * wv.x * rr, v.y * wv.y * rr, v.z * wv.z * rr, v.w * wv.w * rr};
  sx4 oh, ol;
#pragma unroll
  for (int c = 0; c < 4; ++c) {
    short hi = f2bf(vals[c]);
    oh[c] = hi;
    if (SPLIT) ol[c] = f2bf(vals[c] - bf2f(hi));
  }
  ((sx4*)(hh + (long long)row * 1024))[tid] = oh;
  if (SPLIT) ((sx4*)(hl + (long long)row * 1024))[tid] = ol;
}

// ---------------------------------------------------------------------------
// Generic BM x BN MFMA GEMM, C[M,N] = A[M,K] @ Bt[N,K]^T, bf16 inputs.
// NTHR threads (NTHR/64 waves, arranged WRN x WCN; wave tile
// (BM/WRN) x (BN/WCN)). PIPE=0: single buffer; PIPE=1: dbuf, 1 barrier.
// Bijective XCD swizzle (nwg%8==0). TERMS==3: split (Ah*Bh+Ah*Bl+Al*Bh).
// EPI: 1 = split hi/lo bf16; 3 = MoE1 gelu->bf16 (tile table, A rows
//      GATHERED from h2 via row_token); 5 = MoE2 gated bf16 rows;
//      6 = f32 partial (split-K by z).
// ---------------------------------------------------------------------------
struct GemmArgs {
  const short *Ah, *Al, *Bh, *Bl;
  int K, lda, ldb, ldc;
  long long strideBe;
  short *out_h, *out_l;
  float* out_f;
  const float* bias;
  const int* tile_info;  // [80][4]: expert,row0,valid,pad (valid==0 -> dummy)
  const float* row_gate;
  const int* row_token;  // EPI==3: gather map row -> token
};

template <int TERMS, int BM, int BK, int BN, int EPI, int PIPE, int NTHR, int WCN>
__global__ __launch_bounds__(NTHR) void gemm_k(GemmArgs a) {
  const int tid = threadIdx.x, lane = tid & 63, wave = tid >> 6;
  // ---- XCD-aware bijective swizzle of the flat block id (x,y only)
  const int gx = gridDim.x;
  const int nwg = gx * (int)gridDim.y;
  int flat = (int)blockIdx.y * gx + (int)blockIdx.x;
  flat = (flat & 7) * (nwg >> 3) + (flat >> 3);
  const int bx = flat % gx;
  const int by = flat / gx;

  int row0, expert = 0, valid = BM;
  if constexpr (EPI == 3 || EPI == 5) {
    const int* ti = a.tile_info + by * 4;
    expert = ti[0];
    row0 = ti[1];
    valid = ti[2];
    if (valid == 0) return;  // dummy tile (spread evenly across XCDs)
  } else {
    row0 = by * BM;
  }
  const short* Ap = a.Ah;
  const short* Bp = a.Bh + ((EPI == 3 || EPI == 5) ? (long long)expert * a.strideBe : 0ll);
  const int kbeg = blockIdx.z * a.K;  // split-K base (0 when z==1)

  constexpr int CH = BK / 8;             // 16B chunks per row
  constexpr int NIA = (BM * CH) / NTHR;  // A gll16 per thread per K-step
  constexpr int NIB = (BN * CH) / NTHR;  // B gll16 per thread per K-step
  constexpr int ASZ = BM * BK;
  constexpr int BSZ = BN * BK;
  constexpr int WRN = (NTHR / 64) / WCN;  // waves along M
  constexpr int MI = BM / WRN / 16;       // 16-row fragments per wave
  constexpr int TN = BN / WCN / 16;       // 16-col fragments per wave
  constexpr int NB = PIPE ? 2 : 1;

  __shared__ short Ash[NB][ASZ];
  __shared__ short Bsh[NB][BSZ];
  __shared__ short Asl[TERMS == 3 ? NB : 1][TERMS == 3 ? ASZ : 1];
  __shared__ short Bsl[TERMS == 3 ? NB : 1][TERMS == 3 ? BSZ : 1];

  fx4 acc[MI][TN] = {};
  const int wr = wave / WCN, wc = wave % WCN;

  // per-thread A row global offsets (gathered for EPI==3, linear otherwise)
  long long aoff[NIA];
#pragma unroll
  for (int i = 0; i < NIA; ++i) {
    int row = (i * NTHR + tid) / CH;
    if constexpr (EPI == 3)
      aoff[i] = (long long)a.row_token[row0 + row] * a.lda;
    else
      aoff[i] = (long long)(row0 + row) * a.lda;
  }

  auto stage = [&](int s, int k0) {
#pragma unroll
    for (int i = 0; i < NIA; ++i) {
      int t = i * NTHR + tid;
      int row = t / CH, c = t % CH;
      int cc = c ^ swzr<BK>(row);
      int lbase = (i * NTHR + wave * 64) * 8;
      long long acol = kbeg + k0 + cc * 8;
      gll16(Ap + aoff[i] + acol, &Ash[s][lbase]);
      if constexpr (TERMS == 3)
        gll16(a.Al + aoff[i] + acol, &Asl[s][lbase]);
    }
#pragma unroll
    for (int i = 0; i < NIB; ++i) {
      int t = i * NTHR + tid;
      int row = t / CH, c = t % CH;
      int cc = c ^ swzr<BK>(row);
      int lbase = (i * NTHR + wave * 64) * 8;
      long long acol = kbeg + k0 + cc * 8;
      gll16(Bp + (long long)(bx * BN + row) * a.ldb + acol, &Bsh[s][lbase]);
      if constexpr (TERMS == 3)
        gll16(a.Bl + (long long)(bx * BN + row) * a.ldb + acol, &Bsl[s][lbase]);
    }
  };

  auto compute = [&](int s) {
#pragma unroll
    for (int kk = 0; kk < BK / 32; ++kk) {
      sx8 ah[MI], bh[TN], al_[MI], bl_[TN];
#pragma unroll
      for (int mi = 0; mi < MI; ++mi) {
        int row = wr * (BM / WRN) + mi * 16 + (lane & 15);
        int sc = (kk * 4 + (lane >> 4)) ^ swzr<BK>(row);
        ah[mi] = *(const sx8*)&Ash[s][row * BK + sc * 8];
        if constexpr (TERMS == 3) al_[mi] = *(const sx8*)&Asl[s][row * BK + sc * 8];
      }
#pragma unroll
      for (int ni = 0; ni < TN; ++ni) {
        int row = wc * (BN / WCN) + ni * 16 + (lane & 15);
        int sc = (kk * 4 + (lane >> 4)) ^ swzr<BK>(row);
        bh[ni] = *(const sx8*)&Bsh[s][row * BK + sc * 8];
        if constexpr (TERMS == 3) bl_[ni] = *(const sx8*)&Bsl[s][row * BK + sc * 8];
      }
#pragma unroll
      for (int mi = 0; mi < MI; ++mi)
#pragma unroll
        for (int ni = 0; ni < TN; ++ni) {
          acc[mi][ni] = MFMA16(ah[mi], bh[ni], acc[mi][ni]);
          if constexpr (TERMS == 3) {
            acc[mi][ni] = MFMA16(ah[mi], bl_[ni], acc[mi][ni]);
            acc[mi][ni] = MFMA16(al_[mi], bh[ni], acc[mi][ni]);
          }
        }
    }
  };

  const int NT = a.K / BK;
  stage(0, 0);
  __syncthreads();
  for (int t = 0; t < NT; ++t) {
    if constexpr (PIPE) {
      if (t + 1 < NT) stage((t + 1) & 1, (t + 1) * BK);  // prefetch first
      compute(t & 1);
      if (t + 1 < NT) __syncthreads();  // drains prefetch after compute
    } else {
      compute(0);
      if (t + 1 < NT) {
        __syncthreads();
        stage(0, (t + 1) * BK);
        __syncthreads();
      }
    }
  }

  // ---- epilogue (verified write pattern: 16 lanes = 32B/row)
#pragma unroll
  for (int mi = 0; mi < MI; ++mi)
#pragma unroll
    for (int ni = 0; ni < TN; ++ni) {
      fx4 v = acc[mi][ni];
      int rl = wr * (BM / WRN) + mi * 16 + ((lane >> 4) << 2);
      int col = bx * BN + wc * (BN / WCN) + ni * 16 + (lane & 15);
#pragma unroll
      for (int j = 0; j < 4; ++j) {
        int r = rl + j;
        long long grow = (long long)row0 + r;
        float xv = v[j];
        if constexpr (EPI == 1) {
          short hi = f2bf(xv);
          a.out_h[grow * a.ldc + col] = hi;
          a.out_l[grow * a.ldc + col] = f2bf(xv - bf2f(hi));
        } else if constexpr (EPI == 3) {
          xv += a.bias[expert * a.ldc + col];
          a.out_h[grow * a.ldc + col] = f2bf(fast_gelu(xv));
        } else if constexpr (EPI == 5) {
          if (r < valid) {
            xv += a.bias[expert * a.ldc + col];
            float g = a.row_gate[grow];
            a.out_h[grow * a.ldc + col] = f2bf(xv * g);
          }
        } else if constexpr (EPI == 6) {
          a.out_f[(long long)blockIdx.z * 4194304 + grow * a.ldc + col] = xv;
        }
      }
    }
}

// ---------------------------------------------------------------------------
// combine_rms_router_k: out = p0+p1+resid (wo split-K reduce), h2 = rms(out),
// AND router logits/top-2 from the in-register row. One block per token.
// ---------------------------------------------------------------------------
__global__ __launch_bounds__(256) void combine_rms_router_k(
    const float* p0, const float* p1, const float* resid, const float* w,
    const float* rw, float* out, short* h2, int* tok_e, float* tok_g) {
  const int row = blockIdx.x, tid = threadIdx.x;
  const long long base = (long long)row * 1024 + tid * 4;
  fx4 a = *(const fx4*)(p0 + base);
  fx4 b = *(const fx4*)(p1 + base);
  fx4 r = *(const fx4*)(resid + base);
  fx4 o;
  float ss = 0.f;
#pragma unroll
  for (int j = 0; j < 4; ++j) {
    o[j] = a[j] + b[j] + r[j];
    ss += o[j] * o[j];
  }
  *(fx4*)(out + base) = o;
  ss = wsum64(ss);
  __shared__ float red[4];
  if ((tid & 63) == 0) red[tid >> 6] = ss;
  __syncthreads();
  ss = red[0] + red[1] + red[2] + red[3];
  const float rr = rsqrtf(ss * (1.0f / 1024.0f) + 1e-6f);
  const fx4 wv = ((const fx4*)w)[tid];
  fx4 t;
#pragma unroll
  for (int j = 0; j < 4; ++j) t[j] = o[j] * wv[j];
  sx4 oh;
#pragma unroll
  for (int c = 0; c < 4; ++c) oh[c] = f2bf(t[c] * rr);
  ((sx4*)(h2 + (long long)row * 1024))[tid] = oh;

  // ---- router: logits from the in-register normalized row
  float lg[8];
#pragma unroll
  for (int e = 0; e < 8; ++e) {
    fx4 rv = ((const fx4*)(rw + e * 1024))[tid];
    float acc = t[0] * rv[0] + t[1] * rv[1] + t[2] * rv[2] + t[3] * rv[3];
    lg[e] = wsum64(acc);
  }
  __shared__ float lred[8][4];
  if ((tid & 63) == 0) {
#pragma unroll
    for (int e = 0; e < 8; ++e) lred[e][tid >> 6] = lg[e];
  }
  __syncthreads();
  if (tid == 0) {
    float logit[8];
#pragma unroll
    for (int e = 0; e < 8; ++e)
      logit[e] = (lred[e][0] + lred[e][1] + lred[e][2] + lred[e][3]) * rr;
    float mx = logit[0];
#pragma unroll
    for (int e = 1; e < 8; ++e) mx = fmaxf(mx, logit[e]);
    float pe[8];
#pragma unroll
    for (int e = 0; e < 8; ++e) pe[e] = expf(logit[e] - mx);
    int e1 = 0;
    float b1v = pe[0];
#pragma unroll
    for (int e = 1; e < 8; ++e)
      if (pe[e] > b1v) {
        b1v = pe[e];
        e1 = e;
      }
    int e2 = -1;
    float b2v = -1.0f;
#pragma unroll
    for (int e = 0; e < 8; ++e)
      if (e != e1 && pe[e] > b2v) {
        b2v = pe[e];
        e2 = e;
      }
    float inv = 1.0f / (b1v + b2v);
    tok_e[(long long)row * 2] = e1;
    tok_e[(long long)row * 2 + 1] = e2;
    tok_g[(long long)row * 2] = b1v * inv;
    tok_g[(long long)row * 2 + 1] = b2v * inv;
  }
}

// ---------------------------------------------------------------------------
// combine_k: out[tok] += eo[r1] + eo[r2] (gates pre-applied in EPI5).
// ---------------------------------------------------------------------------
__global__ __launch_bounds__(256) void combine_k(const int* row_of_entry,
                                                 const short* eo, float* out) {
  const int tid = threadIdx.x, lane = tid & 63, wave = tid >> 6;
  const long long token = (long long)blockIdx.x * 4 + wave;
  const int r1 = row_of_entry[token * 2];
  const int r2 = row_of_entry[token * 2 + 1];
  const sx8* e1 = (const sx8*)(eo + (long long)r1 * 1024);
  const sx8* e2 = (const sx8*)(eo + (long long)r2 * 1024);
  float* op = out + token * 1024;
#pragma unroll
  for (int half = 0; half < 2; ++half) {
    sx8 va = e1[lane + half * 64];
    sx8 vb = e2[lane + half * 64];
    int cb = (lane + half * 64) * 8;
#pragma unroll
    for (int q = 0; q < 2; ++q) {
      fx4 o = *(const fx4*)(op + cb + q * 4);
#pragma unroll
      for (int j = 0; j < 4; ++j) o[j] += bf2f(va[q * 4 + j]) + bf2f(vb[q * 4 + j]);
      *(fx4*)(op + cb + q * 4) = o;
    }
  }
}

// ---------------------------------------------------------------------------
// Flash attention v4: split-KV work units. 48 units per (b,h):
//  unit<16: whole q-tile qt=unit (kv tiles [0, qt+1), <=16)
//  unit>=16: qt=16+((unit-16)>>1), half=(unit-16)&1:
//    half0 -> kv [0,16) (no diag), half1 -> kv [16, qt+1) (has diag);
//    writes UNNORMALIZED (o,m,l) partials, merged by merge_k.
// 128 threads (2 waves), 32 q-rows/wave. Causal, hd=64, split-bf16 3-term.
// ---------------------------------------------------------------------------
__global__ __launch_bounds__(128, 2) void flash_k(
    const short* __restrict__ qkv_h, const short* __restrict__ qkv_l,
    short* __restrict__ ao_h, short* __restrict__ ao_l, float* __restrict__ opart,
    float* __restrict__ mpart, float* __restrict__ lpart) {
  const int tid = threadIdx.x, lane = tid & 63, wave = tid >> 6;
  const int l15 = lane & 15, g = lane >> 4;
  const int unit = ((int)blockIdx.x + (int)blockIdx.y) % 48;
  const int bh = blockIdx.y;
  const int b = bh >> 4, h = bh & 15;
  const long long base = (long long)b * 2048 * 3072;

  int qt, kt0, kt1, halfp;
  if (unit < 16) {
    qt = unit;
    kt0 = 0;
    kt1 = qt + 1;
    halfp = -1;
  } else {
    int idx = unit - 16;
    qt = 16 + (idx >> 1);
    halfp = idx & 1;
    kt0 = halfp ? 16 : 0;
    kt1 = halfp ? (qt + 1) : 16;
  }
  const int qw = qt * 64 + wave * 32;

  __shared__ short Kh[4096], Kl[4096];      // [64 key][64 d], chunk-swizzled
  __shared__ int VTh[64 * 34], VTl[64 * 34];  // V^T [64 d][32 keypair + pad]

  sx8 qh[2][2], ql[2][2];
#pragma unroll
  for (int mb = 0; mb < 2; ++mb)
#pragma unroll
    for (int kk = 0; kk < 2; ++kk) {
      long long qofs =
          base + (long long)(qw + mb * 16 + l15) * 3072 + h * 64 + kk * 32 + g * 8;
      qh[mb][kk] = *(const sx8*)(qkv_h + qofs);
      ql[mb][kk] = *(const sx8*)(qkv_l + qofs);
    }

  fx4 o[2][4] = {};
  float m_r[2] = {-3e38f, -3e38f}, l_r[2] = {0.f, 0.f};

  const int krow0 = tid >> 3;
  const int kc8 = (tid & 7) * 8;
  const int kswz = ((tid & 7) ^ (krow0 & 7)) * 8;
  const int vu = tid >> 3;
  const int vd0 = (tid & 7) * 8;

  sx8 kr[4], krl[4], vr[4], vrl[4];

  auto load_tile = [&](int kt2) {
    const long long tb = base + (long long)(kt2 * 64) * 3072 + h * 64;
#pragma unroll
    for (int s = 0; s < 4; ++s) {
      long long gofs = tb + 1024 + (long long)(s * 16 + krow0) * 3072 + kc8;
      kr[s] = *(const sx8*)(qkv_h + gofs);
      krl[s] = *(const sx8*)(qkv_l + gofs);
    }
#pragma unroll
    for (int k4 = 0; k4 < 4; ++k4) {
      long long gofs = tb + 2048 + (long long)(4 * vu + k4) * 3072 + vd0;
      vr[k4] = *(const sx8*)(qkv_h + gofs);
      vrl[k4] = *(const sx8*)(qkv_l + gofs);
    }
  };

  load_tile(kt0);

  for (int kt = kt0; kt < kt1; ++kt) {
#pragma unroll
    for (int s = 0; s < 4; ++s) {
      *(sx8*)&Kh[(s * 16 + krow0) * 64 + kswz] = kr[s];
      *(sx8*)&Kl[(s * 16 + krow0) * 64 + kswz] = krl[s];
    }
#pragma unroll
    for (int i = 0; i < 8; ++i) {
      int d = vd0 + i;
      ix2 wh, wl;
      wh[0] = (int)(unsigned short)vr[0][i] | ((int)(unsigned short)vr[1][i] << 16);
      wh[1] = (int)(unsigned short)vr[2][i] | ((int)(unsigned short)vr[3][i] << 16);
      wl[0] = (int)(unsigned short)vrl[0][i] | ((int)(unsigned short)vrl[1][i] << 16);
      wl[1] = (int)(unsigned short)vrl[2][i] | ((int)(unsigned short)vrl[3][i] << 16);
      *(ix2*)&VTh[d * 34 + 2 * vu] = wh;
      *(ix2*)&VTl[d * 34 + 2 * vu] = wl;
    }
    __syncthreads();

    if (kt + 1 < kt1) load_tile(kt + 1);

    const bool diag = (kt == qt);  // last causal tile
    float pvv[2][16];
#pragma unroll
    for (int kc = 0; kc < 4; ++kc) {
      int row = kc * 16 + l15;
      int rsw = row & 7;
      fx4 s0 = {}, s1 = {};
#pragma unroll
      for (int kk = 0; kk < 2; ++kk) {
        int sc = ((kk * 4 + g) ^ rsw) * 8;
        sx8 khf = *(const sx8*)&Kh[row * 64 + sc];
        sx8 klf = *(const sx8*)&Kl[row * 64 + sc];
        s0 = MFMA16(khf, qh[0][kk], s0);
        s1 = MFMA16(khf, qh[1][kk], s1);
        s0 = MFMA16(khf, ql[0][kk], s0);
        s1 = MFMA16(khf, ql[1][kk], s1);
        s0 = MFMA16(klf, qh[0][kk], s0);
        s1 = MFMA16(klf, qh[1][kk], s1);
      }
#pragma unroll
      for (int j = 0; j < 4; ++j) {
        pvv[0][kc * 4 + j] = s0[j];
        pvv[1][kc * 4 + j] = s1[j];
      }
    }

    sx8 pah[2][2], pal[2][2];
#pragma unroll
    for (int mb = 0; mb < 2; ++mb) {
      const int qidx = qw + mb * 16 + l15;
      float t[16];
      float tmax = -3e38f;
#pragma unroll
      for (int i = 0; i < 16; ++i) {
        float sv = pvv[mb][i] * 0.18033688011112f;  // 0.125*log2(e)
        if (diag) {
          int key = kt * 64 + (i >> 2) * 16 + g * 4 + (i & 3);
          sv = (key > qidx) ? -3e38f : sv;
        }
        t[i] = sv;
        tmax = fmaxf(tmax, sv);
      }
      tmax = fmaxf(tmax, __shfl_xor(tmax, 16));
      tmax = fmaxf(tmax, __shfl_xor(tmax, 32));
      if (__any(tmax > m_r[mb] + 8.0f)) {
        float mnew = fmaxf(m_r[mb], tmax);
        float al = exp2f(m_r[mb] - mnew);
        l_r[mb] *= al;
        float aj[4];
#pragma unroll
        for (int j = 0; j < 4; ++j) aj[j] = __shfl(al, (lane & 48) | (g << 2) | j);
#pragma unroll
        for (int f = 0; f < 4; ++f)
#pragma unroll
          for (int j = 0; j < 4; ++j) o[mb][f][j] *= aj[j];
        m_r[mb] = mnew;
      }
      float ps = 0.f;
#pragma unroll
      for (int i = 0; i < 16; ++i) {
        float e = exp2f(t[i] - m_r[mb]);
        t[i] = e;
        ps += e;
      }
      l_r[mb] += ps;
#pragma unroll
      for (int grp = 0; grp < 2; ++grp) {
        ix4 ih, il;
#pragma unroll
        for (int q2 = 0; q2 < 4; ++q2) {
          float a = t[grp * 8 + 2 * q2], bb = t[grp * 8 + 2 * q2 + 1];
          int I = cvt_pk_bf16(a, bb);
          float h0 = __uint_as_float((unsigned)I << 16);
          float h1 = __uint_as_float((unsigned)I & 0xffff0000u);
          int L = cvt_pk_bf16(a - h0, bb - h1);
          ih[q2] = I;
          il[q2] = L;
        }
        pah[mb][grp] = __builtin_bit_cast(sx8, ih);
        pal[mb][grp] = __builtin_bit_cast(sx8, il);
      }
    }

    const ix2* vth = (const ix2*)VTh;
    const ix2* vtl = (const ix2*)VTl;
#pragma unroll
    for (int f = 0; f < 4; ++f) {
      int dd = f * 16 + l15;
      ix2 a0 = vth[dd * 17 + g], a1 = vth[dd * 17 + 4 + g];
      ix2 a2 = vth[dd * 17 + 8 + g], a3 = vth[dd * 17 + 12 + g];
      ix2 c0 = vtl[dd * 17 + g], c1 = vtl[dd * 17 + 4 + g];
      ix2 c2 = vtl[dd * 17 + 8 + g], c3 = vtl[dd * 17 + 12 + g];
      ix4 w;
      w[0] = a0[0]; w[1] = a0[1]; w[2] = a1[0]; w[3] = a1[1];
      sx8 vh8a = __builtin_bit_cast(sx8, w);
      w[0] = a2[0]; w[1] = a2[1]; w[2] = a3[0]; w[3] = a3[1];
      sx8 vh8b = __builtin_bit_cast(sx8, w);
      w[0] = c0[0]; w[1] = c0[1]; w[2] = c1[0]; w[3] = c1[1];
      sx8 vl8a = __builtin_bit_cast(sx8, w);
      w[0] = c2[0]; w[1] = c2[1]; w[2] = c3[0]; w[3] = c3[1];
      sx8 vl8b = __builtin_bit_cast(sx8, w);
#pragma unroll
      for (int mb = 0; mb < 2; ++mb) {
        o[mb][f] = MFMA16(pah[mb][0], vh8a, o[mb][f]);
        o[mb][f] = MFMA16(pah[mb][0], vl8a, o[mb][f]);
        o[mb][f] = MFMA16(pal[mb][0], vh8a, o[mb][f]);
        o[mb][f] = MFMA16(pah[mb][1], vh8b, o[mb][f]);
        o[mb][f] = MFMA16(pah[mb][1], vl8b, o[mb][f]);
        o[mb][f] = MFMA16(pal[mb][1], vh8b, o[mb][f]);
      }
    }
    __syncthreads();
  }

  if (halfp < 0) {
    // ---- full unit: normalize and store split-bf16 ao
#pragma unroll
    for (int mb = 0; mb < 2; ++mb) {
      float lt = l_r[mb];
      lt += __shfl_xor(lt, 16);
      lt += __shfl_xor(lt, 32);
      float linv = 1.0f / lt;
      float lj[4];
#pragma unroll
      for (int j = 0; j < 4; ++j) lj[j] = __shfl(linv, (lane & 48) | (g << 2) | j);
#pragma unroll
      for (int f = 0; f < 4; ++f)
#pragma unroll
        for (int j = 0; j < 4; ++j) {
          float val = o[mb][f][j] * lj[j];
          long long orow = (long long)b * 2048 + qw + mb * 16 + g * 4 + j;
          int ocol = h * 64 + f * 16 + l15;
          short hi = f2bf(val);
          ao_h[orow * 1024 + ocol] = hi;
          ao_l[orow * 1024 + ocol] = f2bf(val - bf2f(hi));
        }
    }
  } else {
    // ---- split unit: write unnormalized partial (o, m, l)
    const int qti = qt - 16;
    const long long pb = (long long)(halfp * 16 + qti) * 32 + bh;
    float* op = opart + pb * 4096;
#pragma unroll
    for (int mb = 0; mb < 2; ++mb) {
      float lt = l_r[mb];
      lt += __shfl_xor(lt, 16);
      lt += __shfl_xor(lt, 32);
      float mj[4], ljv[4];
#pragma unroll
      for (int j = 0; j < 4; ++j) {
        int src = (lane & 48) | (g << 2) | j;
        mj[j] = __shfl(m_r[mb], src);
        ljv[j] = __shfl(lt, src);
      }
#pragma unroll
      for (int f = 0; f < 4; ++f)
#pragma unroll
        for (int j = 0; j < 4; ++j) {
          int r = wave * 32 + mb * 16 + g * 4 + j;
          int d = f * 16 + l15;
          op[r * 64 + d] = o[mb][f][j];
        }
      if (l15 == 0) {
#pragma unroll
        for (int j = 0; j < 4; ++j) {
          int r = wave * 32 + mb * 16 + g * 4 + j;
          mpart[pb * 64 + r] = mj[j];
          lpart[pb * 64 + r] = ljv[j];
        }
      }
    }
  }
}

// ---------------------------------------------------------------------------
// merge_k: two-way online-softmax merge of split-KV partials -> split-bf16 ao.
// grid (16, 32): (qti, bh). 256 threads: r = tid>>2, d-block = (tid&3)*16.
// ---------------------------------------------------------------------------
__global__ __launch_bounds__(256) void merge_k(const float* opart, const float* mpart,
                                               const float* lpart, short* ao_h,
                                               short* ao_l) {
  const int qti = blockIdx.x, bh = blockIdx.y;
  const int b = bh >> 4, h = bh & 15;
  const int tid = threadIdx.x;
  const int r = tid >> 2, d0 = (tid & 3) * 16;
  const long long pb0 = (long long)qti * 32 + bh;
  const long long pb1 = (long long)(16 + qti) * 32 + bh;
  const float m1 = mpart[pb0 * 64 + r], m2 = mpart[pb1 * 64 + r];
  const float l1 = lpart[pb0 * 64 + r], l2 = lpart[pb1 * 64 + r];
  const float M = fmaxf(m1, m2);
  const float w1 = exp2f(m1 - M), w2 = exp2f(m2 - M);
  const float inv = 1.0f / (l1 * w1 + l2 * w2);
  const float* o1 = opart + pb0 * 4096 + r * 64 + d0;
  const float* o2 = opart + pb1 * 4096 + r * 64 + d0;
  const long long orow = (long long)b * 2048 + (16 + qti) * 64 + r;
  const int ocol = h * 64 + d0;
#pragma unroll
  for (int q = 0; q < 4; ++q) {
    fx4 a = *(const fx4*)(o1 + q * 4);
    fx4 c = *(const fx4*)(o2 + q * 4);
#pragma unroll
    for (int j = 0; j < 4; ++j) {
      float val = (a[j] * w1 + c[j] * w2) * inv;
      short hi = f2bf(val);
      ao_h[orow * 1024 + ocol + q * 4 + j] = hi;
      ao_l[orow * 1024 + ocol + q * 4 + j] = f2bf(val - bf2f(hi));
    }
  }
}

// ---------------------------------------------------------------------------
// rank_k: deterministic stable ranking of 8192 (token,slot) entries into
// per-expert segments via packed prefix sums. Single block, 1024 threads.
// FIXED 80-slot table of 128-row tiles; real tile i -> slot i*80/total,
// dummies spread evenly. Zero-fills row_token/row_gate pads (9216 rows).
// ---------------------------------------------------------------------------
__global__ __launch_bounds__(1024) void rank_k(const int* tok_e, const float* tok_g,
                                               int* tinfo, int* row_of_entry,
                                               int* row_token, float* row_gate) {
  const int tid = threadIdx.x, lane = tid & 63, wave = tid >> 6;
  __shared__ unsigned wtot[16][4];
  __shared__ unsigned woff[16][4];
  __shared__ int segsh[8];
  // zero-fill pads (real entries overwritten after the syncs below)
#pragma unroll
  for (int i = 0; i < 9; ++i) {
    int r = tid * 9 + i;
    if (r < 9216) {
      row_token[r] = 0;
      row_gate[r] = 0.f;
    }
  }
  int e[8];
  {
    const int4* te = (const int4*)tok_e;
    int4 a = te[tid * 2], b = te[tid * 2 + 1];
    e[0] = a.x; e[1] = a.y; e[2] = a.z; e[3] = a.w;
    e[4] = b.x; e[5] = b.y; e[6] = b.z; e[7] = b.w;
  }
  unsigned c0 = 0, c1 = 0, c2 = 0, c3 = 0;
#pragma unroll
  for (int i = 0; i < 8; ++i) {
    unsigned f = 1u << ((e[i] & 1) << 4);
    int h = e[i] >> 1;
    c0 += (h == 0) ? f : 0u;
    c1 += (h == 1) ? f : 0u;
    c2 += (h == 2) ? f : 0u;
    c3 += (h == 3) ? f : 0u;
  }
  unsigned s0 = c0, s1 = c1, s2 = c2, s3 = c3;
#pragma unroll
  for (int d = 1; d < 64; d <<= 1) {
    unsigned t0 = __shfl_up(s0, d), t1 = __shfl_up(s1, d);
    unsigned t2 = __shfl_up(s2, d), t3 = __shfl_up(s3, d);
    if (lane >= d) { s0 += t0; s1 += t1; s2 += t2; s3 += t3; }
  }
  if (lane == 63) {
    wtot[wave][0] = s0; wtot[wave][1] = s1; wtot[wave][2] = s2; wtot[wave][3] = s3;
  }
  __syncthreads();
  if (wave == 0 && lane < 16) {
    unsigned v0 = wtot[lane][0], v1 = wtot[lane][1];
    unsigned v2 = wtot[lane][2], v3 = wtot[lane][3];
    unsigned i0 = v0, i1 = v1, i2 = v2, i3 = v3;
#pragma unroll
    for (int d = 1; d < 16; d <<= 1) {
      unsigned t0 = __shfl_up(i0, d), t1 = __shfl_up(i1, d);
      unsigned t2 = __shfl_up(i2, d), t3 = __shfl_up(i3, d);
      if (lane >= d) { i0 += t0; i1 += t1; i2 += t2; i3 += t3; }
    }
    woff[lane][0] = i0 - v0; woff[lane][1] = i1 - v1;
    woff[lane][2] = i2 - v2; woff[lane][3] = i3 - v3;
    if (lane == 15) {
      wtot[0][0] = i0; wtot[0][1] = i1; wtot[0][2] = i2; wtot[0][3] = i3;
    }
  }
  __syncthreads();
  if (tid == 0) {
    int cnt[8], tte[8], total = 0;
    for (int ee = 0; ee < 8; ++ee) {
      unsigned tot = wtot[0][ee >> 1];
      cnt[ee] = (int)((tot >> ((ee & 1) * 16)) & 0xFFFFu);
      tte[ee] = (cnt[ee] + 127) >> 7;
      total += tte[ee];
    }
    for (int s2 = 0; s2 < 80; ++s2) tinfo[s2 * 4 + 2] = 0;  // all dummy
    int off = 0, i = 0;
    for (int ee = 0; ee < 8; ++ee) {
      segsh[ee] = off;
      for (int t2 = 0; t2 < tte[ee]; ++t2) {
        int slot = (i * 80) / total;  // strictly increasing (total <= 71)
        tinfo[slot * 4 + 0] = ee;
        tinfo[slot * 4 + 1] = off + t2 * 128;
        int v = cnt[ee] - t2 * 128;
        tinfo[slot * 4 + 2] = v > 128 ? 128 : v;
        ++i;
      }
      off += tte[ee] << 7;
    }
  }
  __syncthreads();
  unsigned x0 = woff[wave][0] + s0 - c0;
  unsigned x1 = woff[wave][1] + s1 - c1;
  unsigned x2 = woff[wave][2] + s2 - c2;
  unsigned x3 = woff[wave][3] + s3 - c3;
  const int entry0 = tid * 8;
#pragma unroll
  for (int i = 0; i < 8; ++i) {
    int ee = e[i];
    int h = ee >> 1, sh = (ee & 1) << 4;
    unsigned px = (h == 0) ? x0 : (h == 1) ? x1 : (h == 2) ? x2 : x3;
    int rank = (int)((px >> sh) & 0xFFFFu);
    unsigned f = 1u << sh;
    x0 += (h == 0) ? f : 0u;
    x1 += (h == 1) ? f : 0u;
    x2 += (h == 2) ? f : 0u;
    x3 += (h == 3) ? f : 0u;
    int row = segsh[ee] + rank;
    row_of_entry[entry0 + i] = row;
    row_token[row] = (entry0 + i) >> 1;
    row_gate[row] = tok_g[entry0 + i];
  }
}

// ---------------------------------------------------------------------------
// host-side orchestration
// ---------------------------------------------------------------------------
extern "C" void kernel_launch(void* const* d_in, const int* in_sizes, int n_in,
                              void* d_out, int out_size, void* d_ws, size_t ws_size,
                              hipStream_t stream) {
  (void)in_sizes;
  (void)n_in;
  (void)out_size;
  (void)ws_size;
  const float* x = (const float*)d_in[0];
  const float* n1w = (const float*)d_in[1];
  const float* n2w = (const float*)d_in[2];
  const float* wq = (const float*)d_in[3];
  const float* wk = (const float*)d_in[4];
  const float* wv = (const float*)d_in[5];
  const float* wo = (const float*)d_in[6];
  const float* rw = (const float*)d_in[7];
  const float* w1 = (const float*)d_in[8];
  const float* b1 = (const float*)d_in[9];
  const float* w2 = (const float*)d_in[10];
  const float* b2 = (const float*)d_in[11];
  float* out = (float*)d_out;
  char* ws = (char*)d_ws;

  // ---- phase-A layout ----
  short* wqkv_h = (short*)(ws + 0);
  short* wqkv_l = (short*)(ws + 6291456);
  short* wo_h = (short*)(ws + 12582912);
  short* wo_l = (short*)(ws + 14680064);
  short* h_h = (short*)(ws + 16777216);
  short* h_l = (short*)(ws + 25165824);
  short* qkv_h = (short*)(ws + 33554432);
  short* qkv_l = (short*)(ws + 58720256);
  short* ao_h = (short*)(ws + 83886080);
  short* ao_l = (short*)(ws + 92274688);
  // flash split-KV partials overlay the wo_part region (dead during flash)
  float* opart = (float*)(ws + 100663296);   // 16.78 MB: [2][16][32][64][64]
  float* mpart = (float*)(ws + 117440512);   // 256 KB
  float* lpart = (float*)(ws + 117702656);   // 256 KB
  float* wo_part = (float*)(ws + 100663296);  // reused after merge
  // ---- phase-B overlay (all phase-A buffers dead by then) ----
  short* h2 = (short*)(ws + 0);
  short* eo = (short*)(ws + 8388608);      // MoE2 output rows
  short* wslot = (short*)(ws + 27262976);
  int* row_of_entry = (int*)(ws + 94371840);
  short* eh = (short*)(ws + 100663296);    // wo_part dead by then
  // ---- control block ----
  char* ctrl = ws + 176160768;
  int* tinfo = (int*)(ctrl + 128);
  int* tok_e = (int*)(ctrl + 2048);
  float* tok_g = (float*)(ctrl + 2048 + 32768);
  int* row_token = (int*)(ctrl + 2048 + 65536);
  float* row_gate = (float*)(ctrl + 2048 + 65536 + 36864);

  // weight conversion/transpose (split for attention-path weights)
  transpose_k<1><<<dim3(16, 16, 1), 256, 0, stream>>>(wq, wqkv_h, wqkv_l, 1024, 1024);
  transpose_k<1><<<dim3(16, 16, 1), 256, 0, stream>>>(wk, wqkv_h + 1024 * 1024,
                                                      wqkv_l + 1024 * 1024, 1024, 1024);
  transpose_k<1><<<dim3(16, 16, 1), 256, 0, stream>>>(wv, wqkv_h + 2048 * 1024,
                                                      wqkv_l + 2048 * 1024, 1024, 1024);
  transpose_k<1><<<dim3(16, 16, 1), 256, 0, stream>>>(wo, wo_h, wo_l, 1024, 1024);

  rms_k<1><<<4096, 256, 0, stream>>>(x, n1w, h_h, h_l);

  // QKV projection (split, 3-term, dbuf, 512 thr: 16 waves/CU at 64KB LDS)
  {
    GemmArgs a = {};
    a.Ah = h_h;
    a.Al = h_l;
    a.Bh = wqkv_h;
    a.Bl = wqkv_l;
    a.K = 1024;
    a.lda = 1024;
    a.ldb = 1024;
    a.ldc = 3072;
    a.out_h = qkv_h;
    a.out_l = qkv_l;
    gemm_k<3, 128, 32, 128, 1, 1, 512, 4><<<dim3(24, 32), 512, 0, stream>>>(a);
  }

  // flash: 48 split-KV units per (b,h); merge recombines split q-tiles
  flash_k<<<dim3(48, 32), 128, 0, stream>>>(qkv_h, qkv_l, ao_h, ao_l, opart, mpart,
                                            lpart);
  merge_k<<<dim3(16, 32), 256, 0, stream>>>(opart, mpart, lpart, ao_h, ao_l);

  // output projection, split-K x2 -> f32 partials (512 thr)
  {
    GemmArgs a = {};
    a.Ah = ao_h;
    a.Al = ao_l;
    a.Bh = wo_h;
    a.Bl = wo_l;
    a.K = 512;  // per z-split
    a.lda = 1024;
    a.ldb = 1024;
    a.ldc = 1024;
    a.out_f = wo_part;
    gemm_k<3, 128, 32, 128, 6, 1, 512, 4><<<dim3(8, 32, 2), 512, 0, stream>>>(a);
  }
  // out = p0 + p1 + x, h2 = rms(out), router logits + top-2 (all fused)
  combine_rms_router_k<<<4096, 256, 0, stream>>>(wo_part, wo_part + 4194304, x, n2w,
                                                 rw, out, h2, tok_e, tok_g);

  rank_k<<<1, 1024, 0, stream>>>(tok_e, tok_g, tinfo, row_of_entry, row_token,
                                 row_gate);

  // expert GEMM 1: eh = gelu(h2[row_token[r]] @ w1[e] + b1[e])
  // 512 threads (8 waves, 2x4), wave tile 64x32 — R16 proven config
  transpose_k<0><<<dim3(64, 16, 8), 256, 0, stream>>>(w1, wslot, nullptr, 1024, 4096);
  {
    GemmArgs a = {};
    a.Ah = h2;
    a.Bh = wslot;
    a.K = 1024;
    a.lda = 1024;
    a.ldb = 1024;
    a.ldc = 4096;
    a.strideBe = (long long)4096 * 1024;
    a.out_h = eh;
    a.bias = b1;
    a.tile_info = tinfo;
    a.row_token = row_token;
    gemm_k<1, 128, 32, 128, 3, 1, 512, 4><<<dim3(32, 80), 512, 0, stream>>>(a);
  }

  // expert GEMM 2: eo = (eh @ w2[e] + b2[e]) * gate — R16 proven config
  transpose_k<0><<<dim3(16, 64, 8), 256, 0, stream>>>(w2, wslot, nullptr, 4096, 1024);
  {
    GemmArgs a = {};
    a.Ah = eh;
    a.Bh = wslot;
    a.K = 4096;
    a.lda = 4096;
    a.ldb = 4096;
    a.ldc = 1024;
    a.strideBe = (long long)1024 * 4096;
    a.out_h = eo;
    a.bias = b2;
    a.tile_info = tinfo;
    a.row_gate = row_gate;
    gemm_k<1, 128, 32, 128, 5, 1, 512, 4><<<dim3(8, 80), 512, 0, stream>>>(a);
  }

  // out[tok] += eo[r1] + eo[r2]
  combine_k<<<1024, 256, 0, stream>>>(row_of_entry, eo, out);
}

// Round 22
// 614.412 us; speedup vs baseline: 1.0217x; 1.0217x over previous
//
#include <hip/hip_runtime.h>
#include <hip/hip_bf16.h>

// ---------------------------------------------------------------------------
// MoE transformer block on MI355X (gfx950).
// B=2,S=2048,D=1024,H=16,hd=64,F=4096,E=8,K=2, all inputs f32, output f32.
// R22 = terminal configuration = R18/R20 (615us, verified 2x): R16 flash_k
// (qt-swizzled single-tile blocks) + 512-thread BK=32 blocks on all four big
// GEMMs + fused wo-combine/rms/router + gather-in-staging MoE1 + eo/combine
// MoE2. Refuted families: BK=64 (x3), flash pairing, flash split-KV+merge.
// ---------------------------------------------------------------------------

typedef float fx4 __attribute__((ext_vector_type(4)));
typedef short sx4 __attribute__((ext_vector_type(4)));
typedef short sx8 __attribute__((ext_vector_type(8)));
typedef int ix2 __attribute__((ext_vector_type(2)));
typedef int ix4 __attribute__((ext_vector_type(4)));

#define DEVFN static __device__ __forceinline__
#define MFMA16(a, b, c) __builtin_amdgcn_mfma_f32_16x16x32_bf16((a), (b), (c), 0, 0, 0)

typedef __attribute__((address_space(1))) const void GASV;
typedef __attribute__((address_space(3))) void LASV;

DEVFN short f2bf(float f) {
  unsigned u = __float_as_uint(f);
  return (short)((u + 0x7FFFu + ((u >> 16) & 1u)) >> 16);
}
DEVFN float bf2f(short s) { return __uint_as_float(((unsigned)(unsigned short)s) << 16); }

DEVFN int cvt_pk_bf16(float a, float b) {
  int r;
  asm("v_cvt_pk_bf16_f32 %0, %1, %2" : "=v"(r) : "v"(a), "v"(b));
  return r;
}

DEVFN void gll16(const short* g, short* l) {
  __builtin_amdgcn_global_load_lds((GASV*)g, (LASV*)l, 16, 0, 0);
}

// chunk swizzle: BK=64 -> row&7; BK=32 -> fold row bit2 into 2-bit chunk idx.
template <int BK>
DEVFN int swzr(int row) {
  if constexpr (BK == 64)
    return row & 7;
  else
    return (row ^ (row >> 2)) & 3;
}

DEVFN float fast_gelu(float x) {
  // tanh-approx gelu (matches jax.nn.gelu approximate=True)
  float u = 0.7978845608028654f * (x + 0.044715f * x * x * x);
  float e = __expf(2.0f * u);
  float t = 1.0f - 2.0f / (1.0f + e);
  return 0.5f * x * (1.0f + t);
}

DEVFN float wsum64(float v) {
#pragma unroll
  for (int m = 1; m < 64; m <<= 1) v += __shfl_xor(v, m);
  return v;
}

// ---------------------------------------------------------------------------
// transpose+convert: f32 [z][R][C] -> bf16 [z][C][R] (hi, and optional lo)
// ---------------------------------------------------------------------------
template <int SPLIT>
__global__ __launch_bounds__(256) void transpose_k(const float* in, short* oh, short* ol,
                                                   int R, int C) {
  __shared__ float t[64][65];
  const int c0 = blockIdx.x * 64, r0 = blockIdx.y * 64;
  const long long bofs = (long long)blockIdx.z * R * C;
  in += bofs;
  oh += bofs;
  if (SPLIT) ol += bofs;
  const int tid = threadIdx.x;
  const int rr = tid >> 4, cc4 = (tid & 15) * 4;
#pragma unroll
  for (int i = 0; i < 4; ++i) {
    int r = i * 16 + rr;
    fx4 v = *(const fx4*)(in + (long long)(r0 + r) * C + c0 + cc4);
    t[r][cc4] = v.x;
    t[r][cc4 + 1] = v.y;
    t[r][cc4 + 2] = v.z;
    t[r][cc4 + 3] = v.w;
  }
  __syncthreads();
#pragma unroll
  for (int i = 0; i < 4; ++i) {
    int oc = i * 16 + rr;  // output row = c0+oc
    sx4 hv, lv;
#pragma unroll
    for (int j = 0; j < 4; ++j) {
      float v = t[cc4 + j][oc];
      short hi = f2bf(v);
      hv[j] = hi;
      if (SPLIT) lv[j] = f2bf(v - bf2f(hi));
    }
    *(sx4*)(oh + (long long)(c0 + oc) * R + r0 + cc4) = hv;
    if (SPLIT) *(sx4*)(ol + (long long)(c0 + oc) * R + r0 + cc4) = lv;
  }
}

// ---------------------------------------------------------------------------
// RMSNorm: f32 [4096][1024] -> bf16 hi (+lo). one block per row.
// ---------------------------------------------------------------------------
template <int SPLIT>
__global__ __launch_bounds__(256) void rms_k(const float* x, const float* w, short* hh,
                                             short* hl) {
  const int row = blockIdx.x, tid = threadIdx.x;
  const fx4 v = ((const fx4*)(x + (long long)row * 1024))[tid];
  float ss = v.x * v.x + v.y * v.y + v.z * v.z + v.w * v.w;
  ss = wsum64(ss);
  __shared__ float red[4];
  if ((tid & 63) == 0) red[tid >> 6] = ss;
  __syncthreads();
  ss = red[0] + red[1] + red[2] + red[3];
  const float rr = rsqrtf(ss * (1.0f / 1024.0f) + 1e-6f);
  const fx4 wv = ((const fx4*)w)[tid];
  float vals[4] = {v.x * wv.x * rr, v.y * wv.y * rr, v.z * wv.z * rr, v.w * wv.w * rr};
  sx4 oh, ol;
#pragma unroll
  for (int c = 0; c < 4; ++c) {
    short hi = f2bf(vals[c]);
    oh[c] = hi;
    if (SPLIT) ol[c] = f2bf(vals[c] - bf2f(hi));
  }
  ((sx4*)(hh + (long long)row * 1024))[tid] = oh;
  if (SPLIT) ((sx4*)(hl + (long long)row * 1024))[tid] = ol;
}

// ---------------------------------------------------------------------------
// Generic BM x BN MFMA GEMM, C[M,N] = A[M,K] @ Bt[N,K]^T, bf16 inputs.
// NTHR threads (NTHR/64 waves, arranged WRN x WCN; wave tile
// (BM/WRN) x (BN/WCN)). PIPE=0: single buffer; PIPE=1: dbuf, 1 barrier.
// Bijective XCD swizzle (nwg%8==0). TERMS==3: split (Ah*Bh+Ah*Bl+Al*Bh).
// EPI: 1 = split hi/lo bf16; 3 = MoE1 gelu->bf16 (tile table, A rows
//      GATHERED from h2 via row_token); 5 = MoE2 gated bf16 rows;
//      6 = f32 partial (split-K by z).
// ---------------------------------------------------------------------------
struct GemmArgs {
  const short *Ah, *Al, *Bh, *Bl;
  int K, lda, ldb, ldc;
  long long strideBe;
  short *out_h, *out_l;
  float* out_f;
  const float* bias;
  const int* tile_info;  // [80][4]: expert,row0,valid,pad (valid==0 -> dummy)
  const float* row_gate;
  const int* row_token;  // EPI==3: gather map row -> token
};

template <int TERMS, int BM, int BK, int BN, int EPI, int PIPE, int NTHR, int WCN>
__global__ __launch_bounds__(NTHR) void gemm_k(GemmArgs a) {
  const int tid = threadIdx.x, lane = tid & 63, wave = tid >> 6;
  // ---- XCD-aware bijective swizzle of the flat block id (x,y only)
  const int gx = gridDim.x;
  const int nwg = gx * (int)gridDim.y;
  int flat = (int)blockIdx.y * gx + (int)blockIdx.x;
  flat = (flat & 7) * (nwg >> 3) + (flat >> 3);
  const int bx = flat % gx;
  const int by = flat / gx;

  int row0, expert = 0, valid = BM;
  if constexpr (EPI == 3 || EPI == 5) {
    const int* ti = a.tile_info + by * 4;
    expert = ti[0];
    row0 = ti[1];
    valid = ti[2];
    if (valid == 0) return;  // dummy tile (spread evenly across XCDs)
  } else {
    row0 = by * BM;
  }
  const short* Ap = a.Ah;
  const short* Bp = a.Bh + ((EPI == 3 || EPI == 5) ? (long long)expert * a.strideBe : 0ll);
  const int kbeg = blockIdx.z * a.K;  // split-K base (0 when z==1)

  constexpr int CH = BK / 8;             // 16B chunks per row
  constexpr int NIA = (BM * CH) / NTHR;  // A gll16 per thread per K-step
  constexpr int NIB = (BN * CH) / NTHR;  // B gll16 per thread per K-step
  constexpr int ASZ = BM * BK;
  constexpr int BSZ = BN * BK;
  constexpr int WRN = (NTHR / 64) / WCN;  // waves along M
  constexpr int MI = BM / WRN / 16;       // 16-row fragments per wave
  constexpr int TN = BN / WCN / 16;       // 16-col fragments per wave
  constexpr int NB = PIPE ? 2 : 1;

  __shared__ short Ash[NB][ASZ];
  __shared__ short Bsh[NB][BSZ];
  __shared__ short Asl[TERMS == 3 ? NB : 1][TERMS == 3 ? ASZ : 1];
  __shared__ short Bsl[TERMS == 3 ? NB : 1][TERMS == 3 ? BSZ : 1];

  fx4 acc[MI][TN] = {};
  const int wr = wave / WCN, wc = wave % WCN;

  // per-thread A row global offsets (gathered for EPI==3, linear otherwise)
  long long aoff[NIA];
#pragma unroll
  for (int i = 0; i < NIA; ++i) {
    int row = (i * NTHR + tid) / CH;
    if constexpr (EPI == 3)
      aoff[i] = (long long)a.row_token[row0 + row] * a.lda;
    else
      aoff[i] = (long long)(row0 + row) * a.lda;
  }

  auto stage = [&](int s, int k0) {
#pragma unroll
    for (int i = 0; i < NIA; ++i) {
      int t = i * NTHR + tid;
      int row = t / CH, c = t % CH;
      int cc = c ^ swzr<BK>(row);
      int lbase = (i * NTHR + wave * 64) * 8;
      long long acol = kbeg + k0 + cc * 8;
      gll16(Ap + aoff[i] + acol, &Ash[s][lbase]);
      if constexpr (TERMS == 3)
        gll16(a.Al + aoff[i] + acol, &Asl[s][lbase]);
    }
#pragma unroll
    for (int i = 0; i < NIB; ++i) {
      int t = i * NTHR + tid;
      int row = t / CH, c = t % CH;
      int cc = c ^ swzr<BK>(row);
      int lbase = (i * NTHR + wave * 64) * 8;
      long long acol = kbeg + k0 + cc * 8;
      gll16(Bp + (long long)(bx * BN + row) * a.ldb + acol, &Bsh[s][lbase]);
      if constexpr (TERMS == 3)
        gll16(a.Bl + (long long)(bx * BN + row) * a.ldb + acol, &Bsl[s][lbase]);
    }
  };

  auto compute = [&](int s) {
#pragma unroll
    for (int kk = 0; kk < BK / 32; ++kk) {
      sx8 ah[MI], bh[TN], al_[MI], bl_[TN];
#pragma unroll
      for (int mi = 0; mi < MI; ++mi) {
        int row = wr * (BM / WRN) + mi * 16 + (lane & 15);
        int sc = (kk * 4 + (lane >> 4)) ^ swzr<BK>(row);
        ah[mi] = *(const sx8*)&Ash[s][row * BK + sc * 8];
        if constexpr (TERMS == 3) al_[mi] = *(const sx8*)&Asl[s][row * BK + sc * 8];
      }
#pragma unroll
      for (int ni = 0; ni < TN; ++ni) {
        int row = wc * (BN / WCN) + ni * 16 + (lane & 15);
        int sc = (kk * 4 + (lane >> 4)) ^ swzr<BK>(row);
        bh[ni] = *(const sx8*)&Bsh[s][row * BK + sc * 8];
        if constexpr (TERMS == 3) bl_[ni] = *(const sx8*)&Bsl[s][row * BK + sc * 8];
      }
#pragma unroll
      for (int mi = 0; mi < MI; ++mi)
#pragma unroll
        for (int ni = 0; ni < TN; ++ni) {
          acc[mi][ni] = MFMA16(ah[mi], bh[ni], acc[mi][ni]);
          if constexpr (TERMS == 3) {
            acc[mi][ni] = MFMA16(ah[mi], bl_[ni], acc[mi][ni]);
            acc[mi][ni] = MFMA16(al_[mi], bh[ni], acc[mi][ni]);
          }
        }
    }
  };

  const int NT = a.K / BK;
  stage(0, 0);
  __syncthreads();
  for (int t = 0; t < NT; ++t) {
    if constexpr (PIPE) {
      if (t + 1 < NT) stage((t + 1) & 1, (t + 1) * BK);  // prefetch first
      compute(t & 1);
      if (t + 1 < NT) __syncthreads();  // drains prefetch after compute
    } else {
      compute(0);
      if (t + 1 < NT) {
        __syncthreads();
        stage(0, (t + 1) * BK);
        __syncthreads();
      }
    }
  }

  // ---- epilogue (verified write pattern: 16 lanes = 32B/row)
#pragma unroll
  for (int mi = 0; mi < MI; ++mi)
#pragma unroll
    for (int ni = 0; ni < TN; ++ni) {
      fx4 v = acc[mi][ni];
      int rl = wr * (BM / WRN) + mi * 16 + ((lane >> 4) << 2);
      int col = bx * BN + wc * (BN / WCN) + ni * 16 + (lane & 15);
#pragma unroll
      for (int j = 0; j < 4; ++j) {
        int r = rl + j;
        long long grow = (long long)row0 + r;
        float xv = v[j];
        if constexpr (EPI == 1) {
          short hi = f2bf(xv);
          a.out_h[grow * a.ldc + col] = hi;
          a.out_l[grow * a.ldc + col] = f2bf(xv - bf2f(hi));
        } else if constexpr (EPI == 3) {
          xv += a.bias[expert * a.ldc + col];
          a.out_h[grow * a.ldc + col] = f2bf(fast_gelu(xv));
        } else if constexpr (EPI == 5) {
          if (r < valid) {
            xv += a.bias[expert * a.ldc + col];
            float g = a.row_gate[grow];
            a.out_h[grow * a.ldc + col] = f2bf(xv * g);
          }
        } else if constexpr (EPI == 6) {
          a.out_f[(long long)blockIdx.z * 4194304 + grow * a.ldc + col] = xv;
        }
      }
    }
}

// ---------------------------------------------------------------------------
// combine_rms_router_k: out = p0+p1+resid (wo split-K reduce), h2 = rms(out),
// AND router logits/top-2 from the in-register row. One block per token.
// ---------------------------------------------------------------------------
__global__ __launch_bounds__(256) void combine_rms_router_k(
    const float* p0, const float* p1, const float* resid, const float* w,
    const float* rw, float* out, short* h2, int* tok_e, float* tok_g) {
  const int row = blockIdx.x, tid = threadIdx.x;
  const long long base = (long long)row * 1024 + tid * 4;
  fx4 a = *(const fx4*)(p0 + base);
  fx4 b = *(const fx4*)(p1 + base);
  fx4 r = *(const fx4*)(resid + base);
  fx4 o;
  float ss = 0.f;
#pragma unroll
  for (int j = 0; j < 4; ++j) {
    o[j] = a[j] + b[j] + r[j];
    ss += o[j] * o[j];
  }
  *(fx4*)(out + base) = o;
  ss = wsum64(ss);
  __shared__ float red[4];
  if ((tid & 63) == 0) red[tid >> 6] = ss;
  __syncthreads();
  ss = red[0] + red[1] + red[2] + red[3];
  const float rr = rsqrtf(ss * (1.0f / 1024.0f) + 1e-6f);
  const fx4 wv = ((const fx4*)w)[tid];
  fx4 t;
#pragma unroll
  for (int j = 0; j < 4; ++j) t[j] = o[j] * wv[j];
  sx4 oh;
#pragma unroll
  for (int c = 0; c < 4; ++c) oh[c] = f2bf(t[c] * rr);
  ((sx4*)(h2 + (long long)row * 1024))[tid] = oh;

  // ---- router: logits from the in-register normalized row
  float lg[8];
#pragma unroll
  for (int e = 0; e < 8; ++e) {
    fx4 rv = ((const fx4*)(rw + e * 1024))[tid];
    float acc = t[0] * rv[0] + t[1] * rv[1] + t[2] * rv[2] + t[3] * rv[3];
    lg[e] = wsum64(acc);
  }
  __shared__ float lred[8][4];
  if ((tid & 63) == 0) {
#pragma unroll
    for (int e = 0; e < 8; ++e) lred[e][tid >> 6] = lg[e];
  }
  __syncthreads();
  if (tid == 0) {
    float logit[8];
#pragma unroll
    for (int e = 0; e < 8; ++e)
      logit[e] = (lred[e][0] + lred[e][1] + lred[e][2] + lred[e][3]) * rr;
    float mx = logit[0];
#pragma unroll
    for (int e = 1; e < 8; ++e) mx = fmaxf(mx, logit[e]);
    float pe[8];
#pragma unroll
    for (int e = 0; e < 8; ++e) pe[e] = expf(logit[e] - mx);
    int e1 = 0;
    float b1v = pe[0];
#pragma unroll
    for (int e = 1; e < 8; ++e)
      if (pe[e] > b1v) {
        b1v = pe[e];
        e1 = e;
      }
    int e2 = -1;
    float b2v = -1.0f;
#pragma unroll
    for (int e = 0; e < 8; ++e)
      if (e != e1 && pe[e] > b2v) {
        b2v = pe[e];
        e2 = e;
      }
    float inv = 1.0f / (b1v + b2v);
    tok_e[(long long)row * 2] = e1;
    tok_e[(long long)row * 2 + 1] = e2;
    tok_g[(long long)row * 2] = b1v * inv;
    tok_g[(long long)row * 2 + 1] = b2v * inv;
  }
}

// ---------------------------------------------------------------------------
// combine_k: out[tok] += eo[r1] + eo[r2] (gates pre-applied in EPI5).
// ---------------------------------------------------------------------------
__global__ __launch_bounds__(256) void combine_k(const int* row_of_entry,
                                                 const short* eo, float* out) {
  const int tid = threadIdx.x, lane = tid & 63, wave = tid >> 6;
  const long long token = (long long)blockIdx.x * 4 + wave;
  const int r1 = row_of_entry[token * 2];
  const int r2 = row_of_entry[token * 2 + 1];
  const sx8* e1 = (const sx8*)(eo + (long long)r1 * 1024);
  const sx8* e2 = (const sx8*)(eo + (long long)r2 * 1024);
  float* op = out + token * 1024;
#pragma unroll
  for (int half = 0; half < 2; ++half) {
    sx8 va = e1[lane + half * 64];
    sx8 vb = e2[lane + half * 64];
    int cb = (lane + half * 64) * 8;
#pragma unroll
    for (int q = 0; q < 2; ++q) {
      fx4 o = *(const fx4*)(op + cb + q * 4);
#pragma unroll
      for (int j = 0; j < 4; ++j) o[j] += bf2f(va[q * 4 + j]) + bf2f(vb[q * 4 + j]);
      *(fx4*)(op + cb + q * 4) = o;
    }
  }
}

// ---------------------------------------------------------------------------
// Flash attention v2 (R16-proven), causal, hd=64, split-bf16 (3-term).
// grid (32, B*H), 128 threads (2 waves), 32 q-rows/wave, 64-key tiles.
// qt = (bx+by)&31 swizzle for CU load balance.
// ---------------------------------------------------------------------------
__global__ __launch_bounds__(128, 2) void flash_k(const short* __restrict__ qkv_h,
                                                  const short* __restrict__ qkv_l,
                                                  short* __restrict__ ao_h,
                                                  short* __restrict__ ao_l) {
  const int tid = threadIdx.x, lane = tid & 63, wave = tid >> 6;
  const int l15 = lane & 15, g = lane >> 4;
  const int qt = (blockIdx.x + blockIdx.y) & 31;
  const int bh = blockIdx.y;
  const int b = bh >> 4, h = bh & 15;
  const long long base = (long long)b * 2048 * 3072;
  const int qw = qt * 64 + wave * 32;

  __shared__ short Kh[4096], Kl[4096];      // [64 key][64 d], chunk-swizzled
  __shared__ int VTh[64 * 34], VTl[64 * 34];  // V^T [64 d][32 keypair + pad]

  sx8 qh[2][2], ql[2][2];
#pragma unroll
  for (int mb = 0; mb < 2; ++mb)
#pragma unroll
    for (int kk = 0; kk < 2; ++kk) {
      long long qofs =
          base + (long long)(qw + mb * 16 + l15) * 3072 + h * 64 + kk * 32 + g * 8;
      qh[mb][kk] = *(const sx8*)(qkv_h + qofs);
      ql[mb][kk] = *(const sx8*)(qkv_l + qofs);
    }

  fx4 o[2][4] = {};
  float m_r[2] = {-3e38f, -3e38f}, l_r[2] = {0.f, 0.f};

  const int krow0 = tid >> 3;
  const int kc8 = (tid & 7) * 8;
  const int kswz = ((tid & 7) ^ (krow0 & 7)) * 8;
  const int vu = tid >> 3;
  const int vd0 = (tid & 7) * 8;

  sx8 kr[4], krl[4], vr[4], vrl[4];

  auto load_tile = [&](int kt2) {
    const long long tb = base + (long long)(kt2 * 64) * 3072 + h * 64;
#pragma unroll
    for (int s = 0; s < 4; ++s) {
      long long gofs = tb + 1024 + (long long)(s * 16 + krow0) * 3072 + kc8;
      kr[s] = *(const sx8*)(qkv_h + gofs);
      krl[s] = *(const sx8*)(qkv_l + gofs);
    }
#pragma unroll
    for (int k4 = 0; k4 < 4; ++k4) {
      long long gofs = tb + 2048 + (long long)(4 * vu + k4) * 3072 + vd0;
      vr[k4] = *(const sx8*)(qkv_h + gofs);
      vrl[k4] = *(const sx8*)(qkv_l + gofs);
    }
  };

  const int nt = qt + 1;
  load_tile(0);

  for (int kt = 0; kt < nt; ++kt) {
#pragma unroll
    for (int s = 0; s < 4; ++s) {
      *(sx8*)&Kh[(s * 16 + krow0) * 64 + kswz] = kr[s];
      *(sx8*)&Kl[(s * 16 + krow0) * 64 + kswz] = krl[s];
    }
#pragma unroll
    for (int i = 0; i < 8; ++i) {
      int d = vd0 + i;
      ix2 wh, wl;
      wh[0] = (int)(unsigned short)vr[0][i] | ((int)(unsigned short)vr[1][i] << 16);
      wh[1] = (int)(unsigned short)vr[2][i] | ((int)(unsigned short)vr[3][i] << 16);
      wl[0] = (int)(unsigned short)vrl[0][i] | ((int)(unsigned short)vrl[1][i] << 16);
      wl[1] = (int)(unsigned short)vrl[2][i] | ((int)(unsigned short)vrl[3][i] << 16);
      *(ix2*)&VTh[d * 34 + 2 * vu] = wh;
      *(ix2*)&VTl[d * 34 + 2 * vu] = wl;
    }
    __syncthreads();

    if (kt + 1 < nt) load_tile(kt + 1);

    const bool diag = (kt == nt - 1);
    float pvv[2][16];
#pragma unroll
    for (int kc = 0; kc < 4; ++kc) {
      int row = kc * 16 + l15;
      int rsw = row & 7;
      fx4 s0 = {}, s1 = {};
#pragma unroll
      for (int kk = 0; kk < 2; ++kk) {
        int sc = ((kk * 4 + g) ^ rsw) * 8;
        sx8 khf = *(const sx8*)&Kh[row * 64 + sc];
        sx8 klf = *(const sx8*)&Kl[row * 64 + sc];
        s0 = MFMA16(khf, qh[0][kk], s0);
        s1 = MFMA16(khf, qh[1][kk], s1);
        s0 = MFMA16(khf, ql[0][kk], s0);
        s1 = MFMA16(khf, ql[1][kk], s1);
        s0 = MFMA16(klf, qh[0][kk], s0);
        s1 = MFMA16(klf, qh[1][kk], s1);
      }
#pragma unroll
      for (int j = 0; j < 4; ++j) {
        pvv[0][kc * 4 + j] = s0[j];
        pvv[1][kc * 4 + j] = s1[j];
      }
    }

    sx8 pah[2][2], pal[2][2];
#pragma unroll
    for (int mb = 0; mb < 2; ++mb) {
      const int qidx = qw + mb * 16 + l15;
      float t[16];
      float tmax = -3e38f;
#pragma unroll
      for (int i = 0; i < 16; ++i) {
        float sv = pvv[mb][i] * 0.18033688011112f;  // 0.125*log2(e)
        if (diag) {
          int key = kt * 64 + (i >> 2) * 16 + g * 4 + (i & 3);
          sv = (key > qidx) ? -3e38f : sv;
        }
        t[i] = sv;
        tmax = fmaxf(tmax, sv);
      }
      tmax = fmaxf(tmax, __shfl_xor(tmax, 16));
      tmax = fmaxf(tmax, __shfl_xor(tmax, 32));
      if (__any(tmax > m_r[mb] + 8.0f)) {
        float mnew = fmaxf(m_r[mb], tmax);
        float al = exp2f(m_r[mb] - mnew);
        l_r[mb] *= al;
        float aj[4];
#pragma unroll
        for (int j = 0; j < 4; ++j) aj[j] = __shfl(al, (lane & 48) | (g << 2) | j);
#pragma unroll
        for (int f = 0; f < 4; ++f)
#pragma unroll
          for (int j = 0; j < 4; ++j) o[mb][f][j] *= aj[j];
        m_r[mb] = mnew;
      }
      float ps = 0.f;
#pragma unroll
      for (int i = 0; i < 16; ++i) {
        float e = exp2f(t[i] - m_r[mb]);
        t[i] = e;
        ps += e;
      }
      l_r[mb] += ps;
#pragma unroll
      for (int grp = 0; grp < 2; ++grp) {
        ix4 ih, il;
#pragma unroll
        for (int q2 = 0; q2 < 4; ++q2) {
          float a = t[grp * 8 + 2 * q2], bb = t[grp * 8 + 2 * q2 + 1];
          int I = cvt_pk_bf16(a, bb);
          float h0 = __uint_as_float((unsigned)I << 16);
          float h1 = __uint_as_float((unsigned)I & 0xffff0000u);
          int L = cvt_pk_bf16(a - h0, bb - h1);
          ih[q2] = I;
          il[q2] = L;
        }
        pah[mb][grp] = __builtin_bit_cast(sx8, ih);
        pal[mb][grp] = __builtin_bit_cast(sx8, il);
      }
    }

    const ix2* vth = (const ix2*)VTh;
    const ix2* vtl = (const ix2*)VTl;
#pragma unroll
    for (int f = 0; f < 4; ++f) {
      int dd = f * 16 + l15;
      ix2 a0 = vth[dd * 17 + g], a1 = vth[dd * 17 + 4 + g];
      ix2 a2 = vth[dd * 17 + 8 + g], a3 = vth[dd * 17 + 12 + g];
      ix2 c0 = vtl[dd * 17 + g], c1 = vtl[dd * 17 + 4 + g];
      ix2 c2 = vtl[dd * 17 + 8 + g], c3 = vtl[dd * 17 + 12 + g];
      ix4 w;
      w[0] = a0[0]; w[1] = a0[1]; w[2] = a1[0]; w[3] = a1[1];
      sx8 vh8a = __builtin_bit_cast(sx8, w);
      w[0] = a2[0]; w[1] = a2[1]; w[2] = a3[0]; w[3] = a3[1];
      sx8 vh8b = __builtin_bit_cast(sx8, w);
      w[0] = c0[0]; w[1] = c0[1]; w[2] = c1[0]; w[3] = c1[1];
      sx8 vl8a = __builtin_bit_cast(sx8, w);
      w[0] = c2[0]; w[1] = c2[1]; w[2] = c3[0]; w[3] = c3[1];
      sx8 vl8b = __builtin_bit_cast(sx8, w);
#pragma unroll
      for (int mb = 0; mb < 2; ++mb) {
        o[mb][f] = MFMA16(pah[mb][0], vh8a, o[mb][f]);
        o[mb][f] = MFMA16(pah[mb][0], vl8a, o[mb][f]);
        o[mb][f] = MFMA16(pal[mb][0], vh8a, o[mb][f]);
        o[mb][f] = MFMA16(pah[mb][1], vh8b, o[mb][f]);
        o[mb][f] = MFMA16(pah[mb][1], vl8b, o[mb][f]);
        o[mb][f] = MFMA16(pal[mb][1], vh8b, o[mb][f]);
      }
    }
    __syncthreads();
  }

#pragma unroll
  for (int mb = 0; mb < 2; ++mb) {
    float lt = l_r[mb];
    lt += __shfl_xor(lt, 16);
    lt += __shfl_xor(lt, 32);
    float linv = 1.0f / lt;
    float lj[4];
#pragma unroll
    for (int j = 0; j < 4; ++j) lj[j] = __shfl(linv, (lane & 48) | (g << 2) | j);
#pragma unroll
    for (int f = 0; f < 4; ++f)
#pragma unroll
      for (int j = 0; j < 4; ++j) {
        float val = o[mb][f][j] * lj[j];
        long long orow = (long long)b * 2048 + qw + mb * 16 + g * 4 + j;
        int ocol = h * 64 + f * 16 + l15;
        short hi = f2bf(val);
        ao_h[orow * 1024 + ocol] = hi;
        ao_l[orow * 1024 + ocol] = f2bf(val - bf2f(hi));
      }
  }
}

// ---------------------------------------------------------------------------
// rank_k: deterministic stable ranking of 8192 (token,slot) entries into
// per-expert segments via packed prefix sums. Single block, 1024 threads.
// FIXED 80-slot table of 128-row tiles; real tile i -> slot i*80/total,
// dummies spread evenly. Zero-fills row_token/row_gate pads (9216 rows).
// ---------------------------------------------------------------------------
__global__ __launch_bounds__(1024) void rank_k(const int* tok_e, const float* tok_g,
                                               int* tinfo, int* row_of_entry,
                                               int* row_token, float* row_gate) {
  const int tid = threadIdx.x, lane = tid & 63, wave = tid >> 6;
  __shared__ unsigned wtot[16][4];
  __shared__ unsigned woff[16][4];
  __shared__ int segsh[8];
  // zero-fill pads (real entries overwritten after the syncs below)
#pragma unroll
  for (int i = 0; i < 9; ++i) {
    int r = tid * 9 + i;
    if (r < 9216) {
      row_token[r] = 0;
      row_gate[r] = 0.f;
    }
  }
  int e[8];
  {
    const int4* te = (const int4*)tok_e;
    int4 a = te[tid * 2], b = te[tid * 2 + 1];
    e[0] = a.x; e[1] = a.y; e[2] = a.z; e[3] = a.w;
    e[4] = b.x; e[5] = b.y; e[6] = b.z; e[7] = b.w;
  }
  unsigned c0 = 0, c1 = 0, c2 = 0, c3 = 0;
#pragma unroll
  for (int i = 0; i < 8; ++i) {
    unsigned f = 1u << ((e[i] & 1) << 4);
    int h = e[i] >> 1;
    c0 += (h == 0) ? f : 0u;
    c1 += (h == 1) ? f : 0u;
    c2 += (h == 2) ? f : 0u;
    c3 += (h == 3) ? f : 0u;
  }
  unsigned s0 = c0, s1 = c1, s2 = c2, s3 = c3;
#pragma unroll
  for (int d = 1; d < 64; d <<= 1) {
    unsigned t0 = __shfl_up(s0, d), t1 = __shfl_up(s1, d);
    unsigned t2 = __shfl_up(s2, d), t3 = __shfl_up(s3, d);
    if (lane >= d) { s0 += t0; s1 += t1; s2 += t2; s3 += t3; }
  }
  if (lane == 63) {
    wtot[wave][0] = s0; wtot[wave][1] = s1; wtot[wave][2] = s2; wtot[wave][3] = s3;
  }
  __syncthreads();
  if (wave == 0 && lane < 16) {
    unsigned v0 = wtot[lane][0], v1 = wtot[lane][1];
    unsigned v2 = wtot[lane][2], v3 = wtot[lane][3];
    unsigned i0 = v0, i1 = v1, i2 = v2, i3 = v3;
#pragma unroll
    for (int d = 1; d < 16; d <<= 1) {
      unsigned t0 = __shfl_up(i0, d), t1 = __shfl_up(i1, d);
      unsigned t2 = __shfl_up(i2, d), t3 = __shfl_up(i3, d);
      if (lane >= d) { i0 += t0; i1 += t1; i2 += t2; i3 += t3; }
    }
    woff[lane][0] = i0 - v0; woff[lane][1] = i1 - v1;
    woff[lane][2] = i2 - v2; woff[lane][3] = i3 - v3;
    if (lane == 15) {
      wtot[0][0] = i0; wtot[0][1] = i1; wtot[0][2] = i2; wtot[0][3] = i3;
    }
  }
  __syncthreads();
  if (tid == 0) {
    int cnt[8], tte[8], total = 0;
    for (int ee = 0; ee < 8; ++ee) {
      unsigned tot = wtot[0][ee >> 1];
      cnt[ee] = (int)((tot >> ((ee & 1) * 16)) & 0xFFFFu);
      tte[ee] = (cnt[ee] + 127) >> 7;
      total += tte[ee];
    }
    for (int s2 = 0; s2 < 80; ++s2) tinfo[s2 * 4 + 2] = 0;  // all dummy
    int off = 0, i = 0;
    for (int ee = 0; ee < 8; ++ee) {
      segsh[ee] = off;
      for (int t2 = 0; t2 < tte[ee]; ++t2) {
        int slot = (i * 80) / total;  // strictly increasing (total <= 71)
        tinfo[slot * 4 + 0] = ee;
        tinfo[slot * 4 + 1] = off + t2 * 128;
        int v = cnt[ee] - t2 * 128;
        tinfo[slot * 4 + 2] = v > 128 ? 128 : v;
        ++i;
      }
      off += tte[ee] << 7;
    }
  }
  __syncthreads();
  unsigned x0 = woff[wave][0] + s0 - c0;
  unsigned x1 = woff[wave][1] + s1 - c1;
  unsigned x2 = woff[wave][2] + s2 - c2;
  unsigned x3 = woff[wave][3] + s3 - c3;
  const int entry0 = tid * 8;
#pragma unroll
  for (int i = 0; i < 8; ++i) {
    int ee = e[i];
    int h = ee >> 1, sh = (ee & 1) << 4;
    unsigned px = (h == 0) ? x0 : (h == 1) ? x1 : (h == 2) ? x2 : x3;
    int rank = (int)((px >> sh) & 0xFFFFu);
    unsigned f = 1u << sh;
    x0 += (h == 0) ? f : 0u;
    x1 += (h == 1) ? f : 0u;
    x2 += (h == 2) ? f : 0u;
    x3 += (h == 3) ? f : 0u;
    int row = segsh[ee] + rank;
    row_of_entry[entry0 + i] = row;
    row_token[row] = (entry0 + i) >> 1;
    row_gate[row] = tok_g[entry0 + i];
  }
}

// ---------------------------------------------------------------------------
// host-side orchestration
// ---------------------------------------------------------------------------
extern "C" void kernel_launch(void* const* d_in, const int* in_sizes, int n_in,
                              void* d_out, int out_size, void* d_ws, size_t ws_size,
                              hipStream_t stream) {
  (void)in_sizes;
  (void)n_in;
  (void)out_size;
  (void)ws_size;
  const float* x = (const float*)d_in[0];
  const float* n1w = (const float*)d_in[1];
  const float* n2w = (const float*)d_in[2];
  const float* wq = (const float*)d_in[3];
  const float* wk = (const float*)d_in[4];
  const float* wv = (const float*)d_in[5];
  const float* wo = (const float*)d_in[6];
  const float* rw = (const float*)d_in[7];
  const float* w1 = (const float*)d_in[8];
  const float* b1 = (const float*)d_in[9];
  const float* w2 = (const float*)d_in[10];
  const float* b2 = (const float*)d_in[11];
  float* out = (float*)d_out;
  char* ws = (char*)d_ws;

  // ---- phase-A layout ----
  short* wqkv_h = (short*)(ws + 0);
  short* wqkv_l = (short*)(ws + 6291456);
  short* wo_h = (short*)(ws + 12582912);
  short* wo_l = (short*)(ws + 14680064);
  short* h_h = (short*)(ws + 16777216);
  short* h_l = (short*)(ws + 25165824);
  short* qkv_h = (short*)(ws + 33554432);
  short* qkv_l = (short*)(ws + 58720256);
  short* ao_h = (short*)(ws + 83886080);
  short* ao_l = (short*)(ws + 92274688);
  float* wo_part = (float*)(ws + 100663296);  // 2 x 16.78 MB f32 partials
  // ---- phase-B overlay (all phase-A buffers dead by then) ----
  short* h2 = (short*)(ws + 0);
  short* eo = (short*)(ws + 8388608);      // MoE2 output rows
  short* wslot = (short*)(ws + 27262976);
  int* row_of_entry = (int*)(ws + 94371840);
  short* eh = (short*)(ws + 100663296);    // wo_part dead by then
  // ---- control block ----
  char* ctrl = ws + 176160768;
  int* tinfo = (int*)(ctrl + 128);
  int* tok_e = (int*)(ctrl + 2048);
  float* tok_g = (float*)(ctrl + 2048 + 32768);
  int* row_token = (int*)(ctrl + 2048 + 65536);
  float* row_gate = (float*)(ctrl + 2048 + 65536 + 36864);

  // weight conversion/transpose (split for attention-path weights)
  transpose_k<1><<<dim3(16, 16, 1), 256, 0, stream>>>(wq, wqkv_h, wqkv_l, 1024, 1024);
  transpose_k<1><<<dim3(16, 16, 1), 256, 0, stream>>>(wk, wqkv_h + 1024 * 1024,
                                                      wqkv_l + 1024 * 1024, 1024, 1024);
  transpose_k<1><<<dim3(16, 16, 1), 256, 0, stream>>>(wv, wqkv_h + 2048 * 1024,
                                                      wqkv_l + 2048 * 1024, 1024, 1024);
  transpose_k<1><<<dim3(16, 16, 1), 256, 0, stream>>>(wo, wo_h, wo_l, 1024, 1024);

  rms_k<1><<<4096, 256, 0, stream>>>(x, n1w, h_h, h_l);

  // QKV projection (split, 3-term, dbuf, 512 thr: 16 waves/CU at 64KB LDS)
  {
    GemmArgs a = {};
    a.Ah = h_h;
    a.Al = h_l;
    a.Bh = wqkv_h;
    a.Bl = wqkv_l;
    a.K = 1024;
    a.lda = 1024;
    a.ldb = 1024;
    a.ldc = 3072;
    a.out_h = qkv_h;
    a.out_l = qkv_l;
    gemm_k<3, 128, 32, 128, 1, 1, 512, 4><<<dim3(24, 32), 512, 0, stream>>>(a);
  }

  flash_k<<<dim3(32, 32), 128, 0, stream>>>(qkv_h, qkv_l, ao_h, ao_l);

  // output projection, split-K x2 -> f32 partials (512 thr)
  {
    GemmArgs a = {};
    a.Ah = ao_h;
    a.Al = ao_l;
    a.Bh = wo_h;
    a.Bl = wo_l;
    a.K = 512;  // per z-split
    a.lda = 1024;
    a.ldb = 1024;
    a.ldc = 1024;
    a.out_f = wo_part;
    gemm_k<3, 128, 32, 128, 6, 1, 512, 4><<<dim3(8, 32, 2), 512, 0, stream>>>(a);
  }
  // out = p0 + p1 + x, h2 = rms(out), router logits + top-2 (all fused)
  combine_rms_router_k<<<4096, 256, 0, stream>>>(wo_part, wo_part + 4194304, x, n2w,
                                                 rw, out, h2, tok_e, tok_g);

  rank_k<<<1, 1024, 0, stream>>>(tok_e, tok_g, tinfo, row_of_entry, row_token,
                                 row_gate);

  // expert GEMM 1: eh = gelu(h2[row_token[r]] @ w1[e] + b1[e])
  // 512 threads (8 waves, 2x4), wave tile 64x32 — R16 proven config
  transpose_k<0><<<dim3(64, 16, 8), 256, 0, stream>>>(w1, wslot, nullptr, 1024, 4096);
  {
    GemmArgs a = {};
    a.Ah = h2;
    a.Bh = wslot;
    a.K = 1024;
    a.lda = 1024;
    a.ldb = 1024;
    a.ldc = 4096;
    a.strideBe = (long long)4096 * 1024;
    a.out_h = eh;
    a.bias = b1;
    a.tile_info = tinfo;
    a.row_token = row_token;
    gemm_k<1, 128, 32, 128, 3, 1, 512, 4><<<dim3(32, 80), 512, 0, stream>>>(a);
  }

  // expert GEMM 2: eo = (eh @ w2[e] + b2[e]) * gate — R16 proven config
  transpose_k<0><<<dim3(16, 64, 8), 256, 0, stream>>>(w2, wslot, nullptr, 4096, 1024);
  {
    GemmArgs a = {};
    a.Ah = eh;
    a.Bh = wslot;
    a.K = 4096;
    a.lda = 4096;
    a.ldb = 4096;
    a.ldc = 1024;
    a.strideBe = (long long)1024 * 4096;
    a.out_h = eo;
    a.bias = b2;
    a.tile_info = tinfo;
    a.row_gate = row_gate;
    gemm_k<1, 128, 32, 128, 5, 1, 512, 4><<<dim3(8, 80), 512, 0, stream>>>(a);
  }

  // out[tok] += eo[r1] + eo[r2]
  combine_k<<<1024, 256, 0, stream>>>(row_of_entry, eo, out);
}